// Round 16
// baseline (113.463 us; speedup 1.0000x reference)
//
#include <hip/hip_runtime.h>
#include <math.h>

#define H       2880
#define H4      720
#define NTOK    16384
#define NEXP    128
#define NCHUNK  90      // K-chunks of 32 fp32
#define NSTEP   180
#define GAP_EPS 1e-3f   // approx-ranking trust margin (err rms ~7e-6)

typedef __attribute__((ext_vector_type(8)))  short bf16x8;
typedef __attribute__((ext_vector_type(16))) float f32x16;

union FragU { unsigned int u[4]; bf16x8 v; };

// hi = top 16 bits of fp32 (bf16 truncation); lo = bf16(x - hi).
__device__ inline bf16x8 pack_hi2(float4 a, float4 b) {
    const float f[8] = {a.x,a.y,a.z,a.w,b.x,b.y,b.z,b.w};
    FragU r;
#pragma unroll
    for (int j = 0; j < 4; ++j) {
        unsigned u0 = __float_as_uint(f[2*j]);
        unsigned u1 = __float_as_uint(f[2*j+1]);
        r.u[j] = (u1 & 0xFFFF0000u) | (u0 >> 16);
    }
    return r.v;
}
__device__ inline bf16x8 pack_lo2(float4 a, float4 b) {
    const float f[8] = {a.x,a.y,a.z,a.w,b.x,b.y,b.z,b.w};
    FragU r;
#pragma unroll
    for (int j = 0; j < 4; ++j) {
        float x0 = f[2*j],   h0 = __uint_as_float(__float_as_uint(x0) & 0xFFFF0000u);
        float x1 = f[2*j+1], h1 = __uint_as_float(__float_as_uint(x1) & 0xFFFF0000u);
        unsigned l0 = __float_as_uint(x0 - h0);
        unsigned l1 = __float_as_uint(x1 - h1);
        r.u[j] = (l1 & 0xFFFF0000u) | (l0 >> 16);
    }
    return r.v;
}

// ---------------- Kernel 0: w -> bf16 hi/lo planes in MFMA-FRAGMENT order ----------------
__global__ __launch_bounds__(256) void wconv(
    const float* __restrict__ w, short* __restrict__ whiF, short* __restrict__ wloF)
{
    const int gid = blockIdx.x * 256 + threadIdx.x;   // 180*4*64 = 46080
    const int l   = gid & 63;
    const int nt  = (gid >> 6) & 3;
    const int s   = gid >> 8;
    const int e   = nt * 32 + (l & 31);
    const int k0  = s * 16 + (l >> 5) * 8;
    const float4* wp = (const float4*)(w + (size_t)e * H + k0);
    const float4 a = wp[0], b = wp[1];
    *(bf16x8*)(whiF + (size_t)gid * 8) = pack_hi2(a, b);
    *(bf16x8*)(wloF + (size_t)gid * 8) = pack_lo2(a, b);
}

// ---------------- Kernel 1: wave-autonomous MFMA GEMM, 4-deep B prefetch ---------------------
// 1 wave per block (32 tok x 128 exp). A: R9-proven 3-buffer LDS staging (2 chunks ahead).
// B: FOUR static register banks (chunk mod 4 -> bA/bB/bC/bD), loaded 4 chunks ahead
// (~2000+ cy cover vs HBM ~900 cy). Counted vmcnt re-derived: uniform 40 steady state.
__global__ __launch_bounds__(64, 1) void router_gemm_mfma(
    const float* __restrict__ x,
    const short* __restrict__ whiF,
    const short* __restrict__ wloF,
    float* __restrict__ p0,
    float* __restrict__ pws)
{
    __shared__ float xs[3][1024];       // 12 KB, wave-private

    const int lane = threadIdx.x;
    const int bm   = blockIdx.x;        // 0..511
    const int z    = blockIdx.y;
    const int ks   = gridDim.y;
    const int t0   = bm * 32;

    // even-length slices: 90 -> 24/22/22/22 (ks=4); all c0 even, len >= 22
    const int base2 = (NCHUNK / ks) & ~1;
    const int pairs = (NCHUNK - base2 * ks) >> 1;
    const int c0 = z * base2 + 2 * (z < pairs ? z : pairs);
    const int c1 = c0 + base2 + (z < pairs ? 2 : 0);

    float* outp = (z == 0) ? p0 : (pws + (size_t)(z - 1) * NTOK * NEXP);

    // stage source: lane l covers rows (l>>3)+8i, pre-swizzled col (l&7)^(l>>3)
    const float4* gs = (const float4*)x + (size_t)(t0 + (lane >> 3)) * H4 + ((lane & 7) ^ (lane >> 3));
    const unsigned xsb = (unsigned)(uintptr_t)&xs[0][0];
    const int r31 = lane & 31, lx7 = lane & 7, kh2 = (lane >> 5) * 2;

    f32x16 acc[4];
#pragma unroll
    for (int nt = 0; nt < 4; ++nt)
#pragma unroll
        for (int r = 0; r < 16; ++r) acc[nt][r] = 0.0f;

    bf16x8 bA[16], bB[16], bC[16], bD[16];   // static banks: chunk (c-c0) mod 4

#define GL(SRC, DST) __builtin_amdgcn_global_load_lds(                                   \
        (const __attribute__((address_space(1))) void*)(SRC),                            \
        (__attribute__((address_space(3))) void*)(DST), 16, 0, 0)

#define STAGE(SB, CC) {                                                                  \
    const float4* g_ = gs + (size_t)(CC) * 8;                                            \
    GL(g_,                  &xs[SB][0]);                                                 \
    GL(g_ + (size_t) 8*H4,  &xs[SB][256]);                                               \
    GL(g_ + (size_t)16*H4,  &xs[SB][512]);                                               \
    GL(g_ + (size_t)24*H4,  &xs[SB][768]); }

#define BLOAD_ST(DST, CC, ST) {                                                          \
    _Pragma("unroll")                                                                    \
    for (int nt = 0; nt < 4; ++nt) {                                                     \
        const size_t o_ = ((size_t)(((CC)*2 + (ST))*4 + nt)*64 + lane) * 8;              \
        DST[(ST)*8 + nt*2]     = *(const bf16x8*)(whiF + o_);                            \
        DST[(ST)*8 + nt*2 + 1] = *(const bf16x8*)(wloF + o_); } }

#define MFMA_HALF(BANK, ST, AH, AL) {                                                    \
    _Pragma("unroll")                                                                    \
    for (int nt = 0; nt < 4; ++nt) {                                                     \
        acc[nt] = __builtin_amdgcn_mfma_f32_32x32x16_bf16(AH, BANK[(ST)*8 + nt*2],     acc[nt], 0,0,0); \
        acc[nt] = __builtin_amdgcn_mfma_f32_32x32x16_bf16(AL, BANK[(ST)*8 + nt*2],     acc[nt], 0,0,0); \
        acc[nt] = __builtin_amdgcn_mfma_f32_32x32x16_bf16(AH, BANK[(ST)*8 + nt*2 + 1], acc[nt], 0,0,0); } }

#define DSREAD_PACK(BUF) {                                                               \
    const unsigned ab  = xsb + (unsigned)(BUF) * 4096u + (unsigned)r31 * 128u;           \
    const unsigned a00 = ab + 16u * (unsigned)((kh2    ) ^ lx7);                         \
    const unsigned a01 = ab + 16u * (unsigned)((kh2 + 1) ^ lx7);                         \
    const unsigned a10 = ab + 16u * (unsigned)((kh2 + 4) ^ lx7);                         \
    const unsigned a11 = ab + 16u * (unsigned)((kh2 + 5) ^ lx7);                         \
    float4 q0, q1, q2, q3;                                                               \
    asm volatile("ds_read_b128 %0, %1" : "=v"(q0) : "v"(a00) : "memory");                \
    asm volatile("ds_read_b128 %0, %1" : "=v"(q1) : "v"(a01) : "memory");                \
    asm volatile("ds_read_b128 %0, %1" : "=v"(q2) : "v"(a10) : "memory");                \
    asm volatile("s_waitcnt lgkmcnt(0)" ::: "memory");                                   \
    asm volatile("ds_read_b128 %0, %1" : "=v"(q3) : "v"(a11) : "memory");                \
    asm volatile("s_waitcnt lgkmcnt(0)" ::: "memory");                                   \
    __builtin_amdgcn_sched_barrier(0);                                                   \
    ah0 = pack_hi2(q0, q1); al0 = pack_lo2(q0, q1);                                      \
    ah1 = pack_hi2(q2, q3); al1 = pack_lo2(q2, q3); }

#define VMW(N) asm volatile("s_waitcnt vmcnt(" #N ")" ::: "memory")

    // prologue: S(c0)->b0, S(c0+1)->b1, B for first 4 chunks (72 ops in flight)
    STAGE(0, c0);
    STAGE(1, c0 + 1);
    BLOAD_ST(bA, c0, 0);     BLOAD_ST(bA, c0, 1);
    BLOAD_ST(bB, c0 + 1, 0); BLOAD_ST(bB, c0 + 1, 1);
    BLOAD_ST(bC, c0 + 2, 0); BLOAD_ST(bC, c0 + 2, 1);
    BLOAD_ST(bD, c0 + 3, 0); BLOAD_ST(bD, c0 + 3, 1);

    bf16x8 ah0, al0, ah1, al1;
    int rb0 = 0;                        // A-buffer of chunk c: (c-c0)%3

    // main loop: 4 chunks/iter; all steady waits = 40 (derived by issue-order trace;
    // first iter true counts >= 40 -> over-wait, safe). B loaded 4 chunks ahead.
    int c = c0;
    for (; c + 8 <= c1; c += 4) {
        const int b0 = rb0;
        const int b1 = (rb0 + 1 >= 3) ? rb0 - 2 : rb0 + 1;
        const int b2 = (rb0 + 2 >= 3) ? rb0 - 1 : rb0 + 2;
        STAGE(b2, c + 2);
        VMW(40);                        // S(c)
        DSREAD_PACK(b0);
        MFMA_HALF(bA, 0, ah0, al0);  BLOAD_ST(bA, c + 4, 0);
        MFMA_HALF(bA, 1, ah1, al1);  BLOAD_ST(bA, c + 4, 1);
        STAGE(b0, c + 3);               // b0 drained at lgkmcnt(0)
        VMW(40);                        // S(c+1)
        DSREAD_PACK(b1);
        MFMA_HALF(bB, 0, ah0, al0);  BLOAD_ST(bB, c + 5, 0);
        MFMA_HALF(bB, 1, ah1, al1);  BLOAD_ST(bB, c + 5, 1);
        STAGE(b1, c + 4);
        VMW(40);                        // S(c+2)
        DSREAD_PACK(b2);
        MFMA_HALF(bC, 0, ah0, al0);  BLOAD_ST(bC, c + 6, 0);
        MFMA_HALF(bC, 1, ah1, al1);  BLOAD_ST(bC, c + 6, 1);
        STAGE(b2, c + 5);               // b2 drained at lgkmcnt(0)
        VMW(40);                        // S(c+3)
        DSREAD_PACK(b0);                // buf(c+3) = b0 (restaged above)
        MFMA_HALF(bD, 0, ah0, al0);  BLOAD_ST(bD, c + 7, 0);
        MFMA_HALF(bD, 1, ah1, al1);  BLOAD_ST(bD, c + 7, 1);
        rb0 = (rb0 + 1 >= 3) ? 0 : rb0 + 1;   // (c+4-c0)%3
    }

    // tail: r = c1 - c chunks remain, r in {4, 6}; (c - c0) % 4 == 0 -> banks bA..bD in order
    {
        const int b0 = rb0;
        const int b1 = (rb0 + 1 >= 3) ? rb0 - 2 : rb0 + 1;
        const int b2 = (rb0 + 2 >= 3) ? rb0 - 1 : rb0 + 2;
        if (c1 - c == 6) {
            STAGE(b2, c + 2);
            VMW(40);                    // S(t0): 36 prev + 4 = 40
            DSREAD_PACK(b0);
            MFMA_HALF(bA, 0, ah0, al0);  BLOAD_ST(bA, c + 4, 0);
            MFMA_HALF(bA, 1, ah1, al1);  BLOAD_ST(bA, c + 4, 1);
            STAGE(b0, c + 3);
            VMW(40);                    // S(t1): 16+4+16+4 = 40
            DSREAD_PACK(b1);
            MFMA_HALF(bB, 0, ah0, al0);  BLOAD_ST(bB, c + 5, 0);
            MFMA_HALF(bB, 1, ah1, al1);  BLOAD_ST(bB, c + 5, 1);
            STAGE(b1, c + 4);
            VMW(40);                    // S(t2): 16+4+16+4 = 40
            DSREAD_PACK(b2);
            MFMA_HALF(bC, 0, ah0, al0);
            MFMA_HALF(bC, 1, ah1, al1);
            STAGE(b2, c + 5);           // b2 drained
            VMW(24);                    // S(t3): 16+4+4 = 24
            DSREAD_PACK(b0);            // buf(t3) = b0
            MFMA_HALF(bD, 0, ah0, al0);
            MFMA_HALF(bD, 1, ah1, al1);
            VMW(4);                     // S(t4): S(t5)4 younger
            DSREAD_PACK(b1);            // buf(t4) = b1
            MFMA_HALF(bA, 0, ah0, al0);
            MFMA_HALF(bA, 1, ah1, al1);
            VMW(0);                     // S(t5)
            DSREAD_PACK(b2);            // buf(t5) = b2
            MFMA_HALF(bB, 0, ah0, al0);
            MFMA_HALF(bB, 1, ah1, al1);
        } else {                        // r == 4
            STAGE(b2, c + 2);
            VMW(40);                    // S(t0)
            DSREAD_PACK(b0);
            MFMA_HALF(bA, 0, ah0, al0);
            MFMA_HALF(bA, 1, ah1, al1);
            STAGE(b0, c + 3);
            VMW(24);                    // S(t1): BLD(t3)16 + S(t2)4 + S(t3)4
            DSREAD_PACK(b1);
            MFMA_HALF(bB, 0, ah0, al0);
            MFMA_HALF(bB, 1, ah1, al1);
            VMW(4);                     // S(t2): S(t3)4 younger
            DSREAD_PACK(b2);
            MFMA_HALF(bC, 0, ah0, al0);
            MFMA_HALF(bC, 1, ah1, al1);
            VMW(0);                     // S(t3)
            DSREAD_PACK(b0);            // buf(t3) = b0
            MFMA_HALF(bD, 0, ah0, al0);
            MFMA_HALF(bD, 1, ah1, al1);
        }
    }

    // D layout (32x32): col = lane&31, row = (r&3) + 8*(r>>2) + 4*(lane>>5)  [verified]
    const int ecol  = lane & 31;
    const int rbase = t0 + 4 * (lane >> 5);
#pragma unroll
    for (int nt = 0; nt < 4; ++nt)
#pragma unroll
        for (int r = 0; r < 16; ++r) {
            const int orow = rbase + (r & 3) + 8 * (r >> 2);
            outp[(size_t)orow * NEXP + nt * 32 + ecol] = acc[nt][r];
        }
}

// ---------------- Kernel 2: reduce + bias -> logits; top-8; gap-gated fast path --------------
// R9-proven verbatim.
__global__ __launch_bounds__(256) void reduce_cand(
    float* __restrict__ p0,
    const float* __restrict__ pws,
    const float* __restrict__ bias,
    int* __restrict__ cand,             // [NTOK][8]; cand[t*8] bit30 = needs exact fixup
    float* __restrict__ vals,
    float* __restrict__ inds,
    int ks)
{
    const int tid = threadIdx.x;
    const int tok = blockIdx.x * 8 + (tid >> 5);
    const int l   = tid & 31;

    float4* row = (float4*)p0 + (size_t)tok * 32 + l;
    float4 s = row[0];
    for (int zz = 1; zz < ks; ++zz) {
        const float4 pz = ((const float4*)(pws + (size_t)(zz - 1) * NTOK * NEXP))[(size_t)tok * 32 + l];
        s.x += pz.x; s.y += pz.y; s.z += pz.z; s.w += pz.w;
    }
    const float4 bb = ((const float4*)bias)[l];
    s.x += bb.x; s.y += bb.y; s.z += bb.z; s.w += bb.w;
    row[0] = s;                         // final (approx) logits

    float v[4] = {s.x, s.y, s.z, s.w};
    float vv[8]; int out[8];
#pragma unroll
    for (int r = 0; r < 8; ++r) {
        float lv = v[0]; int lj = 0;
#pragma unroll
        for (int j = 1; j < 4; ++j) if (v[j] > lv) { lv = v[j]; lj = j; }
        int le = l * 4 + lj;
#pragma unroll
        for (int m = 1; m < 32; m <<= 1) {
            const float ov = __shfl_xor(lv, m, 32);
            const int   oe = __shfl_xor(le, m, 32);
            if (ov > lv || (ov == lv && oe < le)) { lv = ov; le = oe; }
        }
        vv[r] = lv; out[r] = le;
        if ((le >> 2) == l) v[le & 3] = -3.4e38f;
    }

    float ming = vv[0] - vv[1];
    ming = fminf(ming, vv[1] - vv[2]);
    ming = fminf(ming, vv[2] - vv[3]);
    ming = fminf(ming, vv[3] - vv[4]);
    const bool slow = (ming < GAP_EPS);

    if (l == 0) {
        int4 o0 = {out[0] | (slow ? (1 << 30) : 0), out[1], out[2], out[3]};
        int4 o1 = {out[4], out[5], out[6], out[7]};
        *(int4*)(cand + (size_t)tok * 8)     = o0;
        *(int4*)(cand + (size_t)tok * 8 + 4) = o1;
        if (!slow) {
            const float e1 = expf(vv[1] - vv[0]);
            const float e2 = expf(vv[2] - vv[0]);
            const float e3 = expf(vv[3] - vv[0]);
            const float sm = 1.0f + e1 + e2 + e3;
            float4 ov = {1.0f / sm, e1 / sm, e2 / sm, e3 / sm};
            float4 oi = {(float)out[0], (float)out[1], (float)out[2], (float)out[3]};
            *(float4*)(&vals[(size_t)tok * 4]) = ov;
            *(float4*)(&inds[(size_t)tok * 4]) = oi;
        }
    }
}

// ---------------- Kernel 3: exact fp64 recompute, only for flagged tokens --------------------
__global__ __launch_bounds__(256) void fixup_topk(
    const float* __restrict__ x,
    const float* __restrict__ w,
    const float* __restrict__ bias,
    const int* __restrict__ cand,
    float* __restrict__ vals,
    float* __restrict__ inds)
{
    const int lane = threadIdx.x & 63;
    const int wv   = threadIdx.x >> 6;
    const int tok  = blockIdx.x * 4 + wv;

    const int head = cand[(size_t)tok * 8];
    if (!(head & (1 << 30))) return;    // fast-path token, already written

    const int c    = lane >> 3;
    const int s    = lane & 7;
    const int cidx = cand[(size_t)tok * 8 + c] & 0x3fffffff;

    const float4* xr = (const float4*)x + (size_t)tok  * H4;
    const float4* wr = (const float4*)w + (size_t)cidx * H4;

    double acc = 0.0;
    for (int j = 0; j < 90; ++j) {
        const float4 a = xr[s + 8 * j];
        const float4 b = wr[s + 8 * j];
        acc = fma((double)a.x, (double)b.x, acc);
        acc = fma((double)a.y, (double)b.y, acc);
        acc = fma((double)a.z, (double)b.z, acc);
        acc = fma((double)a.w, (double)b.w, acc);
    }
    acc += __shfl_xor(acc, 1);
    acc += __shfl_xor(acc, 2);
    acc += __shfl_xor(acc, 4);
    const double exact = acc + (double)bias[cidx];

    double bv[8]; int bidx[8];
#pragma unroll
    for (int g = 0; g < 8; ++g) { bv[g] = __shfl(exact, g * 8); bidx[g] = __shfl(cidx, g * 8); }

    float fv[4]; int fi[4];
#pragma unroll
    for (int k = 0; k < 4; ++k) {
        double best = -1.0e300; int bi = 1 << 30; int bg = -1;
#pragma unroll
        for (int g = 0; g < 8; ++g) {
            if (bv[g] > best || (bv[g] == best && bidx[g] < bi)) { best = bv[g]; bi = bidx[g]; bg = g; }
        }
#pragma unroll
        for (int g = 0; g < 8; ++g) if (g == bg) bv[g] = -1.0e300;
        fv[k] = (float)best; fi[k] = bi;
    }

    if (lane == 0) {
        const float e1 = expf(fv[1] - fv[0]);
        const float e2 = expf(fv[2] - fv[0]);
        const float e3 = expf(fv[3] - fv[0]);
        const float sm = 1.0f + e1 + e2 + e3;
        float4 ov = {1.0f / sm, e1 / sm, e2 / sm, e3 / sm};
        float4 oi = {(float)fi[0], (float)fi[1], (float)fi[2], (float)fi[3]};
        *(float4*)(&vals[(size_t)tok * 4]) = ov;
        *(float4*)(&inds[(size_t)tok * 4]) = oi;
    }
}

extern "C" void kernel_launch(void* const* d_in, const int* in_sizes, int n_in,
                              void* d_out, int out_size, void* d_ws, size_t ws_size,
                              hipStream_t stream) {
    const float* x    = (const float*)d_in[0];
    const float* w    = (const float*)d_in[1];
    const float* bias = (const float*)d_in[2];

    float* out    = (float*)d_out;
    float* vals   = out;                 // 16384*4
    float* inds   = out + NTOK * 4;      // 16384*4
    float* logits = out + NTOK * 8;      // 16384*128

    const size_t WPLANE = (size_t)NEXP * H * sizeof(short);      // 737280 B
    const size_t PB     = (size_t)NTOK * NEXP * sizeof(float);   // 8.39 MB
    const size_t CB     = (size_t)NTOK * 8 * sizeof(int);        // 512 KB

    int ks = 1;
    if      (ws_size >= 2 * WPLANE + 3 * PB + CB) ks = 4;
    else if (ws_size >= 2 * WPLANE + 1 * PB + CB) ks = 2;

    short* whiF = (short*)d_ws;
    short* wloF = whiF + (size_t)NEXP * H;
    float* pws  = (float*)(wloF + (size_t)NEXP * H);
    int*   cand = (int*)(pws + (size_t)(ks - 1) * NTOK * NEXP);

    wconv<<<NSTEP, 256, 0, stream>>>(w, whiF, wloF);
    router_gemm_mfma<<<dim3(NTOK / 32, ks), 64, 0, stream>>>(x, whiF, wloF, logits, pws);
    reduce_cand<<<NTOK / 8, 256, 0, stream>>>(logits, pws, bias, cand, vals, inds, ks);
    fixup_topk<<<NTOK / 4, 256, 0, stream>>>(x, w, bias, cand, vals, inds);
}

// Round 17
// 81.554 us; speedup vs baseline: 1.3913x; 1.3913x over previous
//
#include <hip/hip_runtime.h>
#include <math.h>

#define H       2880
#define H4      720
#define NTOK    16384
#define NEXP    128
#define NCHUNK  90      // K-chunks of 32 fp32
#define NSTEP   180
#define KSW     4       // intra-block K-split (one wave per slice)
#define GAP_EPS 1e-3f   // approx-ranking trust margin (err rms ~7e-6)

typedef __attribute__((ext_vector_type(8)))  short bf16x8;
typedef __attribute__((ext_vector_type(16))) float f32x16;

union FragU { unsigned int u[4]; bf16x8 v; };

// hi = top 16 bits of fp32 (bf16 truncation); lo = bf16(x - hi).
__device__ inline bf16x8 pack_hi2(float4 a, float4 b) {
    const float f[8] = {a.x,a.y,a.z,a.w,b.x,b.y,b.z,b.w};
    FragU r;
#pragma unroll
    for (int j = 0; j < 4; ++j) {
        unsigned u0 = __float_as_uint(f[2*j]);
        unsigned u1 = __float_as_uint(f[2*j+1]);
        r.u[j] = (u1 & 0xFFFF0000u) | (u0 >> 16);
    }
    return r.v;
}
__device__ inline bf16x8 pack_lo2(float4 a, float4 b) {
    const float f[8] = {a.x,a.y,a.z,a.w,b.x,b.y,b.z,b.w};
    FragU r;
#pragma unroll
    for (int j = 0; j < 4; ++j) {
        float x0 = f[2*j],   h0 = __uint_as_float(__float_as_uint(x0) & 0xFFFF0000u);
        float x1 = f[2*j+1], h1 = __uint_as_float(__float_as_uint(x1) & 0xFFFF0000u);
        unsigned l0 = __float_as_uint(x0 - h0);
        unsigned l1 = __float_as_uint(x1 - h1);
        r.u[j] = (l1 & 0xFFFF0000u) | (l0 >> 16);
    }
    return r.v;
}

// ---------------- Kernel 0: w -> bf16 hi/lo planes in MFMA-FRAGMENT order ----------------
__global__ __launch_bounds__(256) void wconv(
    const float* __restrict__ w, short* __restrict__ whiF, short* __restrict__ wloF)
{
    const int gid = blockIdx.x * 256 + threadIdx.x;   // 180*4*64 = 46080
    const int l   = gid & 63;
    const int nt  = (gid >> 6) & 3;
    const int s   = gid >> 8;
    const int e   = nt * 32 + (l & 31);
    const int k0  = s * 16 + (l >> 5) * 8;
    const float4* wp = (const float4*)(w + (size_t)e * H + k0);
    const float4 a = wp[0], b = wp[1];
    *(bf16x8*)(whiF + (size_t)gid * 8) = pack_hi2(a, b);
    *(bf16x8*)(wloF + (size_t)gid * 8) = pack_lo2(a, b);
}

// ---------------- Kernel 1: MFMA GEMM, intra-block split-K, LEAN fused reduce ---------------
// 512 blocks x 4 waves. Wave wv runs the R9-proven pipeline VERBATIM on K-slice wv
// (wave-private 12 KB LDS, per-wave counted vmcnt, no barriers in the loop).
// Tail (all statically indexed -- no runtime-indexed arrays, rule-20 safe):
//   barrier -> waves 1-3 dump acc into dead staging LDS -> barrier ->
//   wave 0: combine fixed order + bias -> write FINAL logits once. Top-k in kernel 2.
__global__ __launch_bounds__(256, 2) void router_gemm_fused(
    const float* __restrict__ x,
    const short* __restrict__ whiF,
    const short* __restrict__ wloF,
    const float* __restrict__ bias,
    float* __restrict__ logits)
{
    __shared__ float xs[4][3][1024];    // 48 KB staging; reused as acc-exchange after loop

    const int tid  = threadIdx.x;
    const int lane = tid & 63;
    const int wv   = tid >> 6;
    const int bm   = blockIdx.x;        // 0..511
    const int t0   = bm * 32;

    // even-length K slices per wave: 24/22/22/22, all c0 even
    const int base2 = (NCHUNK / KSW) & ~1;
    const int pairs = (NCHUNK - base2 * KSW) >> 1;
    const int c0 = wv * base2 + 2 * (wv < pairs ? wv : pairs);
    const int c1 = c0 + base2 + (wv < pairs ? 2 : 0);

    // stage source: lane l covers rows (l>>3)+8i, pre-swizzled col (l&7)^(l>>3)
    const float4* gs = (const float4*)x + (size_t)(t0 + (lane >> 3)) * H4 + ((lane & 7) ^ (lane >> 3));
    const unsigned xsb = (unsigned)(uintptr_t)&xs[wv][0][0];
    const int r31 = lane & 31, lx7 = lane & 7, kh2 = (lane >> 5) * 2;

    f32x16 acc[4];
#pragma unroll
    for (int nt = 0; nt < 4; ++nt)
#pragma unroll
        for (int r = 0; r < 16; ++r) acc[nt][r] = 0.0f;

    bf16x8 bA[16], bB[16];              // static banks: even / odd chunks

#define GL(SRC, DST) __builtin_amdgcn_global_load_lds(                                   \
        (const __attribute__((address_space(1))) void*)(SRC),                            \
        (__attribute__((address_space(3))) void*)(DST), 16, 0, 0)

#define STAGE(SB, CC) {                                                                  \
    const float4* g_ = gs + (size_t)(CC) * 8;                                            \
    GL(g_,                  &xs[wv][SB][0]);                                             \
    GL(g_ + (size_t) 8*H4,  &xs[wv][SB][256]);                                           \
    GL(g_ + (size_t)16*H4,  &xs[wv][SB][512]);                                           \
    GL(g_ + (size_t)24*H4,  &xs[wv][SB][768]); }

#define BLOAD_ST(DST, CC, ST) {                                                          \
    _Pragma("unroll")                                                                    \
    for (int nt = 0; nt < 4; ++nt) {                                                     \
        const size_t o_ = ((size_t)(((CC)*2 + (ST))*4 + nt)*64 + lane) * 8;              \
        DST[(ST)*8 + nt*2]     = *(const bf16x8*)(whiF + o_);                            \
        DST[(ST)*8 + nt*2 + 1] = *(const bf16x8*)(wloF + o_); } }

#define MFMA_HALF(BANK, ST, AH, AL) {                                                    \
    _Pragma("unroll")                                                                    \
    for (int nt = 0; nt < 4; ++nt) {                                                     \
        acc[nt] = __builtin_amdgcn_mfma_f32_32x32x16_bf16(AH, BANK[(ST)*8 + nt*2],     acc[nt], 0,0,0); \
        acc[nt] = __builtin_amdgcn_mfma_f32_32x32x16_bf16(AL, BANK[(ST)*8 + nt*2],     acc[nt], 0,0,0); \
        acc[nt] = __builtin_amdgcn_mfma_f32_32x32x16_bf16(AH, BANK[(ST)*8 + nt*2 + 1], acc[nt], 0,0,0); } }

#define DSREAD_PACK(BUF, AH0, AL0, AH1, AL1) {                                           \
    const unsigned ab  = xsb + (unsigned)(BUF) * 4096u + (unsigned)r31 * 128u;           \
    const unsigned a00 = ab + 16u * (unsigned)((kh2    ) ^ lx7);                         \
    const unsigned a01 = ab + 16u * (unsigned)((kh2 + 1) ^ lx7);                         \
    const unsigned a10 = ab + 16u * (unsigned)((kh2 + 4) ^ lx7);                         \
    const unsigned a11 = ab + 16u * (unsigned)((kh2 + 5) ^ lx7);                         \
    float4 q0, q1, q2, q3;                                                               \
    asm volatile("ds_read_b128 %0, %1" : "=v"(q0) : "v"(a00) : "memory");                \
    asm volatile("ds_read_b128 %0, %1" : "=v"(q1) : "v"(a01) : "memory");                \
    asm volatile("ds_read_b128 %0, %1" : "=v"(q2) : "v"(a10) : "memory");                \
    asm volatile("ds_read_b128 %0, %1" : "=v"(q3) : "v"(a11) : "memory");                \
    asm volatile("s_waitcnt lgkmcnt(0)" ::: "memory");                                   \
    __builtin_amdgcn_sched_barrier(0);                                                   \
    AH0 = pack_hi2(q0, q1); AL0 = pack_lo2(q0, q1);                                      \
    AH1 = pack_hi2(q2, q3); AL1 = pack_lo2(q2, q3); }

    // ---- R9-proven pipeline, verbatim (vmcnt is per-wave state; counts unchanged) ----
    STAGE(0, c0);
    STAGE(1, c0 + 1);
    BLOAD_ST(bA, c0, 0);     BLOAD_ST(bA, c0, 1);
    BLOAD_ST(bB, c0 + 1, 0); BLOAD_ST(bB, c0 + 1, 1);

    int rb = 0;
    bf16x8 ah0, al0, ah1, al1;
    for (int c = c0; c < c1 - 2; c += 2) {
        const int sb  = (rb + 2 >= 3) ? rb - 1 : rb + 2;
        const int rb1 = (rb + 1 >= 3) ? 0 : rb + 1;
        STAGE(sb, c + 2);
        asm volatile("s_waitcnt vmcnt(40)" ::: "memory");
        DSREAD_PACK(rb, ah0, al0, ah1, al1);
        MFMA_HALF(bA, 0, ah0, al0);
        BLOAD_ST(bA, c + 2, 0);
        MFMA_HALF(bA, 1, ah1, al1);
        BLOAD_ST(bA, c + 2, 1);
        STAGE(rb, c + 3);
        asm volatile("s_waitcnt vmcnt(40)" ::: "memory");
        DSREAD_PACK(rb1, ah0, al0, ah1, al1);
        MFMA_HALF(bB, 0, ah0, al0);
        BLOAD_ST(bB, c + 3, 0);
        MFMA_HALF(bB, 1, ah1, al1);
        BLOAD_ST(bB, c + 3, 1);
        rb = (rb >= 1) ? rb - 1 : 2;
    }
    {
        const int rb1 = (rb + 1 >= 3) ? 0 : rb + 1;
        asm volatile("s_waitcnt vmcnt(36)" ::: "memory");
        DSREAD_PACK(rb, ah0, al0, ah1, al1);
        MFMA_HALF(bA, 0, ah0, al0);
        MFMA_HALF(bA, 1, ah1, al1);
        asm volatile("s_waitcnt vmcnt(16)" ::: "memory");
        DSREAD_PACK(rb1, ah0, al0, ah1, al1);
        MFMA_HALF(bB, 0, ah0, al0);
        MFMA_HALF(bB, 1, ah1, al1);
    }

    // ---- lean fused tail: combine partial accs through the (now dead) staging LDS ----
    __syncthreads();                    // all waves done with staging LDS
    float* exch = &xs[0][0][0];         // 3 x 16 KB regions
    if (wv > 0) {
        const int eb = (wv - 1) * 4096;
#pragma unroll
        for (int nt = 0; nt < 4; ++nt)
#pragma unroll
            for (int r = 0; r < 16; ++r)
                exch[eb + (nt * 16 + r) * 64 + lane] = acc[nt][r];  // lane-consecutive
    }
    __syncthreads();
    if (wv != 0) return;

    // combine (fixed order -> deterministic) + bias, write FINAL logits once
    const int l31 = lane & 31;
    const float bv0 = bias[l31], bv1 = bias[32 + l31], bv2 = bias[64 + l31], bv3 = bias[96 + l31];
    const int rbase = t0 + 4 * (lane >> 5);
#pragma unroll
    for (int nt = 0; nt < 4; ++nt) {
        const float bb = (nt == 0) ? bv0 : (nt == 1) ? bv1 : (nt == 2) ? bv2 : bv3;
#pragma unroll
        for (int r = 0; r < 16; ++r) {
            const int sl = (nt * 16 + r) * 64 + lane;
            const float v = ((acc[nt][r] + exch[sl]) + exch[4096 + sl]) + exch[8192 + sl] + bb;
            const int orow = rbase + (r & 3) + 8 * (r >> 2);
            logits[(size_t)orow * NEXP + nt * 32 + l31] = v;
        }
    }
}

// ---------------- Kernel 2: READ-ONLY top-8 over final logits; gap gate; fast softmax --------
// Lean (low VGPR): reads 33 MB logits, writes cand + fast-path outputs only.
__global__ __launch_bounds__(256) void topk_cand(
    const float* __restrict__ logits,
    int* __restrict__ cand,             // [NTOK][8]; cand[t*8] bit30 = needs exact fixup
    float* __restrict__ vals,
    float* __restrict__ inds)
{
    const int tid = threadIdx.x;
    const int tok = blockIdx.x * 8 + (tid >> 5);
    const int l   = tid & 31;

    const float4 s = ((const float4*)logits)[(size_t)tok * 32 + l];

    float v[4] = {s.x, s.y, s.z, s.w};
    float vv[8]; int out[8];
#pragma unroll
    for (int r = 0; r < 8; ++r) {
        float lv = v[0]; int lj = 0;
#pragma unroll
        for (int j = 1; j < 4; ++j) if (v[j] > lv) { lv = v[j]; lj = j; }
        int le = l * 4 + lj;
#pragma unroll
        for (int m = 1; m < 32; m <<= 1) {      // width-32 butterfly, tie -> lower index
            const float ov = __shfl_xor(lv, m, 32);
            const int   oe = __shfl_xor(le, m, 32);
            if (ov > lv || (ov == lv && oe < le)) { lv = ov; le = oe; }
        }
        vv[r] = lv; out[r] = le;
        if ((le >> 2) == l) v[le & 3] = -3.4e38f;
    }

    float ming = vv[0] - vv[1];
    ming = fminf(ming, vv[1] - vv[2]);
    ming = fminf(ming, vv[2] - vv[3]);
    ming = fminf(ming, vv[3] - vv[4]);
    const bool slow = (ming < GAP_EPS);

    if (l == 0) {
        int4 o0 = {out[0] | (slow ? (1 << 30) : 0), out[1], out[2], out[3]};
        int4 o1 = {out[4], out[5], out[6], out[7]};
        *(int4*)(cand + (size_t)tok * 8)     = o0;
        *(int4*)(cand + (size_t)tok * 8 + 4) = o1;
        if (!slow) {
            const float e1 = expf(vv[1] - vv[0]);
            const float e2 = expf(vv[2] - vv[0]);
            const float e3 = expf(vv[3] - vv[0]);
            const float sm = 1.0f + e1 + e2 + e3;
            float4 ov = {1.0f / sm, e1 / sm, e2 / sm, e3 / sm};
            float4 oi = {(float)out[0], (float)out[1], (float)out[2], (float)out[3]};
            *(float4*)(&vals[(size_t)tok * 4]) = ov;
            *(float4*)(&inds[(size_t)tok * 4]) = oi;
        }
    }
}

// ---------------- Kernel 3: exact fp64 recompute, only for flagged tokens --------------------
__global__ __launch_bounds__(256) void fixup_topk(
    const float* __restrict__ x,
    const float* __restrict__ w,
    const float* __restrict__ bias,
    const int* __restrict__ cand,
    float* __restrict__ vals,
    float* __restrict__ inds)
{
    const int lane = threadIdx.x & 63;
    const int wv   = threadIdx.x >> 6;
    const int tok  = blockIdx.x * 4 + wv;

    const int head = cand[(size_t)tok * 8];
    if (!(head & (1 << 30))) return;    // fast-path token, already written

    const int c    = lane >> 3;
    const int s    = lane & 7;
    const int cidx = cand[(size_t)tok * 8 + c] & 0x3fffffff;

    const float4* xr = (const float4*)x + (size_t)tok  * H4;
    const float4* wr = (const float4*)w + (size_t)cidx * H4;

    double acc = 0.0;
    for (int j = 0; j < 90; ++j) {
        const float4 a = xr[s + 8 * j];
        const float4 b = wr[s + 8 * j];
        acc = fma((double)a.x, (double)b.x, acc);
        acc = fma((double)a.y, (double)b.y, acc);
        acc = fma((double)a.z, (double)b.z, acc);
        acc = fma((double)a.w, (double)b.w, acc);
    }
    acc += __shfl_xor(acc, 1);
    acc += __shfl_xor(acc, 2);
    acc += __shfl_xor(acc, 4);
    const double exact = acc + (double)bias[cidx];

    double bv[8]; int bidx[8];
#pragma unroll
    for (int g = 0; g < 8; ++g) { bv[g] = __shfl(exact, g * 8); bidx[g] = __shfl(cidx, g * 8); }

    float fv[4]; int fi[4];
#pragma unroll
    for (int k = 0; k < 4; ++k) {
        double best = -1.0e300; int bi = 1 << 30; int bg = -1;
#pragma unroll
        for (int g = 0; g < 8; ++g) {
            if (bv[g] > best || (bv[g] == best && bidx[g] < bi)) { best = bv[g]; bi = bidx[g]; bg = g; }
        }
#pragma unroll
        for (int g = 0; g < 8; ++g) if (g == bg) bv[g] = -1.0e300;
        fv[k] = (float)best; fi[k] = bi;
    }

    if (lane == 0) {
        const float e1 = expf(fv[1] - fv[0]);
        const float e2 = expf(fv[2] - fv[0]);
        const float e3 = expf(fv[3] - fv[0]);
        const float sm = 1.0f + e1 + e2 + e3;
        float4 ov = {1.0f / sm, e1 / sm, e2 / sm, e3 / sm};
        float4 oi = {(float)fi[0], (float)fi[1], (float)fi[2], (float)fi[3]};
        *(float4*)(&vals[(size_t)tok * 4]) = ov;
        *(float4*)(&inds[(size_t)tok * 4]) = oi;
    }
}

extern "C" void kernel_launch(void* const* d_in, const int* in_sizes, int n_in,
                              void* d_out, int out_size, void* d_ws, size_t ws_size,
                              hipStream_t stream) {
    const float* x    = (const float*)d_in[0];
    const float* w    = (const float*)d_in[1];
    const float* bias = (const float*)d_in[2];

    float* out    = (float*)d_out;
    float* vals   = out;                 // 16384*4
    float* inds   = out + NTOK * 4;      // 16384*4
    float* logits = out + NTOK * 8;      // 16384*128

    // ws layout: whiF | wloF | cand  (~2 MB; no split-K partials)
    short* whiF = (short*)d_ws;
    short* wloF = whiF + (size_t)NEXP * H;
    int*   cand = (int*)(wloF + (size_t)NEXP * H);

    wconv<<<NSTEP, 256, 0, stream>>>(w, whiF, wloF);
    router_gemm_fused<<<NTOK / 32, 256, 0, stream>>>(x, whiF, wloF, bias, logits);
    topk_cand<<<NTOK / 8, 256, 0, stream>>>(logits, cand, vals, inds);
    fixup_topk<<<NTOK / 4, 256, 0, stream>>>(x, w, bias, cand, vals, inds);
}